// Round 1
// baseline (4983.820 us; speedup 1.0000x reference)
//
#include <hip/hip_runtime.h>

// Problem constants (from reference)
#define O_N 2000
#define T_N 6000
#define DIN 2048
#define DW  300
#define DG  512
#define HH_ 512

constexpr int TBM = 64, TBN = 64, TBK = 16;

// C = act(A_or_concat @ W + bias)
// A row-major (M x K eff). Concat mode (Tab != null): col k < KA from A (lda),
// else Tab[idx[r*idxStride]] row (DWc wide). W row-major K x N (ldw == N).
// Accuracy: fp32 fma within each K=16 tile, promoted to fp64 across tiles.
__global__ __launch_bounds__(256) void gemm_f64acc(
    const float* __restrict__ A, int lda,
    const float* __restrict__ Tab, int KA, int DWc,
    const int* __restrict__ idx, int idxStride,
    const float* __restrict__ W,
    const float* __restrict__ bias, int doRelu,
    float* __restrict__ C, int ldc,
    int M, int N, int K)
{
    __shared__ float As[TBK][TBM + 4];
    __shared__ float Bs[TBK][TBN + 4];
    const int tx = threadIdx.x, ty = threadIdx.y;
    const int tid = ty * 16 + tx;
    const int n0 = blockIdx.x * TBN, m0 = blockIdx.y * TBM;

    double acc[4][4];
#pragma unroll
    for (int i = 0; i < 4; i++)
#pragma unroll
        for (int j = 0; j < 4; j++) acc[i][j] = 0.0;

    const int aRow = tid >> 2, aK = (tid & 3) << 2;
    const int bK = tid >> 4, bC = (tid & 15) << 2;
    const int rA = m0 + aRow;

    for (int k0 = 0; k0 < K; k0 += TBK) {
        // ---- stage A tile (64 rows x 16 k), float4 per thread ----
        float4 av = make_float4(0.f, 0.f, 0.f, 0.f);
        int k = k0 + aK;                  // K always %4==0 here (2348/2048/512)
        if (rA < M && k < K) {
            const float* src;
            if (Tab == nullptr || k < KA)
                src = A + (size_t)rA * lda + k;
            else
                src = Tab + (size_t)idx[(size_t)rA * idxStride] * DWc + (k - KA);
            av = *(const float4*)src;
        }
        As[aK + 0][aRow] = av.x;
        As[aK + 1][aRow] = av.y;
        As[aK + 2][aRow] = av.z;
        As[aK + 3][aRow] = av.w;

        // ---- stage B tile (16 k x 64 cols) ----
        float4 bv = make_float4(0.f, 0.f, 0.f, 0.f);
        int kb = k0 + bK;
        if (kb < K) bv = *(const float4*)(W + (size_t)kb * N + n0 + bC);
        *(float4*)&Bs[bK][bC] = bv;

        __syncthreads();

        // ---- fp32 within tile, fp64 across tiles ----
        float facc[4][4];
#pragma unroll
        for (int i = 0; i < 4; i++)
#pragma unroll
            for (int j = 0; j < 4; j++) facc[i][j] = 0.f;

#pragma unroll
        for (int kk = 0; kk < TBK; kk++) {
            const float4 a = *(const float4*)&As[kk][ty << 2];
            const float4 b = *(const float4*)&Bs[kk][tx << 2];
            const float ar[4] = {a.x, a.y, a.z, a.w};
            const float br[4] = {b.x, b.y, b.z, b.w};
#pragma unroll
            for (int i = 0; i < 4; i++)
#pragma unroll
                for (int j = 0; j < 4; j++)
                    facc[i][j] = fmaf(ar[i], br[j], facc[i][j]);
        }
#pragma unroll
        for (int i = 0; i < 4; i++)
#pragma unroll
            for (int j = 0; j < 4; j++) acc[i][j] += (double)facc[i][j];

        __syncthreads();
    }

    // ---- epilogue ----
#pragma unroll
    for (int i = 0; i < 4; i++) {
        int r = m0 + (ty << 2) + i;
        if (r < M) {
            float4 o;
            float vals[4];
#pragma unroll
            for (int j = 0; j < 4; j++) {
                int c = n0 + (tx << 2) + j;
                double v = acc[i][j];
                if (bias) v += (double)bias[c];
                float f = (float)v;
                if (doRelu) f = fmaxf(f, 0.f);
                vals[j] = f;
            }
            o.x = vals[0]; o.y = vals[1]; o.z = vals[2]; o.w = vals[3];
            *(float4*)(C + (size_t)r * ldc + n0 + (tx << 2)) = o;
        }
    }
}

// t[e,:] = relu(P1[s[e],:] + PP[e,:] + P2[o[e],:] + b1a)
__global__ void edge_combine(const float* __restrict__ P1,
                             const float* __restrict__ PP,
                             const float* __restrict__ P2,
                             const int* __restrict__ rels,
                             const float* __restrict__ b1a,
                             float* __restrict__ TT)
{
    int e = blockIdx.x;
    int j = threadIdx.x << 2;       // 128 threads * 4 = 512
    int s = rels[e * 3 + 0];
    int o = rels[e * 3 + 2];
    float4 v1 = *(const float4*)(P1 + (size_t)s * HH_ + j);
    float4 vp = *(const float4*)(PP + (size_t)e * HH_ + j);
    float4 v2 = *(const float4*)(P2 + (size_t)o * HH_ + j);
    float4 vb = *(const float4*)(b1a + j);
    float4 r;
    r.x = fmaxf(v1.x + vp.x + v2.x + vb.x, 0.f);
    r.y = fmaxf(v1.y + vp.y + v2.y + vb.y, 0.f);
    r.z = fmaxf(v1.z + vp.z + v2.z + vb.z, 0.f);
    r.w = fmaxf(v1.w + vp.w + v2.w + vb.w, 0.f);
    *(float4*)(TT + (size_t)e * HH_ + j) = r;
}

// pooled[s[e]] += t2[e, 0:512]; pooled[o[e]] += t2[e, 1024:1536]; counts
__global__ void scatter_pool(const float* __restrict__ T2,
                             const int* __restrict__ rels,
                             double* __restrict__ PO,
                             int* __restrict__ CNT)
{
    int e = blockIdx.x;
    int t = threadIdx.x;            // 256
    int s = rels[e * 3 + 0];
    int o = rels[e * 3 + 2];
#pragma unroll
    for (int u = 0; u < 2; u++) {
        int j = t + u * 256;
        unsafeAtomicAdd(PO + (size_t)s * HH_ + j, (double)T2[(size_t)e * 1536 + j]);
        unsafeAtomicAdd(PO + (size_t)o * HH_ + j, (double)T2[(size_t)e * 1536 + 1024 + j]);
    }
    if (t == 0) {
        atomicAdd(CNT + s, 1);
        atomicAdd(CNT + o, 1);
    }
}

__global__ void pool_div(const double* __restrict__ PO,
                         const int* __restrict__ CNT,
                         float* __restrict__ out)
{
    int i = blockIdx.x * 256 + threadIdx.x;
    if (i >= O_N * HH_) return;
    int r = i >> 9;
    int c = CNT[r]; if (c < 1) c = 1;
    out[i] = (float)(PO[i] / (double)c);
}

// dst[e, 0:512] = T2[e, 512:1024]
__global__ void copy_pred(const float* __restrict__ T2, float* __restrict__ dst)
{
    int i = blockIdx.x * 256 + threadIdx.x;   // float4 index
    if (i >= T_N * HH_ / 4) return;
    int e = i / (HH_ / 4);
    int j = (i % (HH_ / 4)) << 2;
    float4 v = *(const float4*)(T2 + (size_t)e * 1536 + 512 + j);
    *(float4*)(dst + (size_t)e * HH_ + j) = v;
}

static inline void gemm_launch(hipStream_t st, const float* A, int lda,
                               const float* Tab, int KA, int DWc,
                               const int* idx, int idxs,
                               const float* W, const float* bias, int relu_,
                               float* C, int ldc, int M, int N, int K)
{
    dim3 g(N / TBN, (M + TBM - 1) / TBM), b(16, 16);
    hipLaunchKernelGGL(gemm_f64acc, g, b, 0, st, A, lda, Tab, KA, DWc, idx, idxs,
                       W, bias, relu_, C, ldc, M, N, K);
}

extern "C" void kernel_launch(void* const* d_in, const int* in_sizes, int n_in,
                              void* d_out, int out_size, void* d_ws, size_t ws_size,
                              hipStream_t stream)
{
    const float* obj_embs  = (const float*)d_in[0];
    const float* pred_embs = (const float*)d_in[2];
    const int*   rels      = (const int*)d_in[4];
    const int*   objs      = (const int*)d_in[5];
    const float* obj_table = (const float*)d_in[6];
    const float* rel_table = (const float*)d_in[7];
    const float* Wf_obj = (const float*)d_in[8];
    const float* bf_obj = (const float*)d_in[9];
    const float* Wf_rel = (const float*)d_in[10];
    const float* bf_rel = (const float*)d_in[11];
    const float* W1a = (const float*)d_in[12];
    const float* b1a = (const float*)d_in[13];
    const float* W1b = (const float*)d_in[14];
    const float* b1b = (const float*)d_in[15];
    const float* W2a = (const float*)d_in[16];
    const float* b2a = (const float*)d_in[17];
    const float* W2b = (const float*)d_in[18];
    const float* b2b = (const float*)d_in[19];
    const float* Ws1a = (const float*)d_in[20];
    const float* bs1a = (const float*)d_in[21];
    const float* Ws1b = (const float*)d_in[22];
    const float* bs1b = (const float*)d_in[23];
    const float* Ws2a = (const float*)d_in[24];
    const float* bs2a = (const float*)d_in[25];
    const float* Ws2b = (const float*)d_in[26];
    const float* bs2b = (const float*)d_in[27];
    float* out = (float*)d_out;

    // workspace layout (fp32 elements unless noted); total ~143.4 MB
    float* base = (float*)d_ws;
    float* OV = base;                              // 2000*2048
    float* PV = OV + (size_t)O_N * DIN;            // 6000*2048
    float* P1 = PV + (size_t)T_N * DIN;            // 2000*512
    float* P2 = P1 + (size_t)O_N * HH_;            // 2000*512
    float* PP = P2 + (size_t)O_N * HH_;            // 6000*512
    float* TT = PP + (size_t)T_N * HH_;            // 6000*512
    float* T2 = TT + (size_t)T_N * HH_;            // 6000*1536
    double* PO = (double*)(T2 + (size_t)T_N * 1536); // 2000*512 doubles
    int* CNT = (int*)(PO + (size_t)O_N * HH_);     // 2000 ints

    // input projections (concat with table lookup fused into A-load)
    gemm_launch(stream, obj_embs, DIN, obj_table, DIN, DW, objs, 1,
                Wf_obj, bf_obj, 1, OV, DIN, O_N, DIN, DIN + DW);
    gemm_launch(stream, pred_embs, DIN, rel_table, DIN, DW, rels + 1, 3,
                Wf_rel, bf_rel, 1, PV, DIN, T_N, DIN, DIN + DW);

    for (int L = 0; L < 5; L++) {
        const int D = (L == 0) ? DIN : HH_;
        const float* w1a  = (L == 0) ? W1a : (Ws1a + (size_t)(L - 1) * 3 * HH_ * HH_);
        const float* bb1a = (L == 0) ? b1a : (bs1a + (size_t)(L - 1) * HH_);
        const float* w1b  = (L == 0) ? W1b : (Ws1b + (size_t)(L - 1) * HH_ * 1536);
        const float* bb1b = (L == 0) ? b1b : (bs1b + (size_t)(L - 1) * 1536);
        const float* w2a  = (L == 0) ? W2a : (Ws2a + (size_t)(L - 1) * HH_ * HH_);
        const float* bb2a = (L == 0) ? b2a : (bs2a + (size_t)(L - 1) * HH_);
        const float* w2b  = (L == 0) ? W2b : (Ws2b + (size_t)(L - 1) * HH_ * DG);
        const float* bb2b = (L == 0) ? b2b : (bs2b + (size_t)(L - 1) * DG);
        const float* w1a_top = w1a;
        const float* w1a_mid = w1a + (size_t)D * HH_;
        const float* w1a_bot = w1a + (size_t)2 * D * HH_;

        // cur @ W1a decomposed: P1 = OV@top, PP = PV@mid, P2 = OV@bot
        gemm_launch(stream, OV, D, nullptr, 0, 0, nullptr, 0,
                    w1a_top, nullptr, 0, P1, HH_, O_N, HH_, D);
        gemm_launch(stream, PV, D, nullptr, 0, 0, nullptr, 0,
                    w1a_mid, nullptr, 0, PP, HH_, T_N, HH_, D);
        gemm_launch(stream, OV, D, nullptr, 0, 0, nullptr, 0,
                    w1a_bot, nullptr, 0, P2, HH_, O_N, HH_, D);

        hipLaunchKernelGGL(edge_combine, dim3(T_N), dim3(128), 0, stream,
                           P1, PP, P2, rels, bb1a, TT);

        // t2 = relu(t @ W1b + b1b)
        gemm_launch(stream, TT, HH_, nullptr, 0, 0, nullptr, 0,
                    w1b, bb1b, 1, T2, 1536, T_N, 1536, HH_);

        // pooling (fp64 atomics, int counts)
        hipMemsetAsync(PO, 0, (size_t)O_N * HH_ * sizeof(double), stream);
        hipMemsetAsync(CNT, 0, (size_t)O_N * sizeof(int), stream);
        hipLaunchKernelGGL(scatter_pool, dim3(T_N), dim3(256), 0, stream,
                           T2, rels, PO, CNT);
        hipLaunchKernelGGL(pool_div, dim3((O_N * HH_ + 255) / 256), dim3(256), 0, stream,
                           PO, CNT, P1);

        // obj MLP2: h = relu(pooled@W2a+b2a) -> PP (reuse), obj = relu(h@W2b+b2b)
        gemm_launch(stream, P1, HH_, nullptr, 0, 0, nullptr, 0,
                    w2a, bb2a, 1, PP, HH_, O_N, HH_, HH_);
        float* objDst = (L == 4) ? out : OV;   // ld 512 next layer
        gemm_launch(stream, PP, HH_, nullptr, 0, 0, nullptr, 0,
                    w2b, bb2b, 1, objDst, HH_, O_N, DG, HH_);

        float* predDst = (L == 4) ? (out + (size_t)O_N * DG) : PV;
        hipLaunchKernelGGL(copy_pred, dim3((T_N * HH_ / 4 + 255) / 256), dim3(256), 0, stream,
                           T2, predDst);
    }
}

// Round 2
// 4465.383 us; speedup vs baseline: 1.1161x; 1.1161x over previous
//
#include <hip/hip_runtime.h>

#define O_N 2000
#define T_N 6000
#define DIN 2048
#define DW  300
#define DG  512
#define HH_ 512

constexpr int TBN = 64, TBK = 16;

__device__ __forceinline__ float4 ld4(const float* p) { return *(const float4*)p; }

// Fused GEMM: C = act(Afetch @ W + bias), fp32 FMA within K=32 chunks promoted
// to fp64 across chunks.
// MODE 0: A plain row-major (lda)
// MODE 1: concat — col k<KA from A, else Tab[idx[r*idxStride]] (DWc wide)
// MODE 2: edge-combine — relu(P1v[s[r]]+A[r]+P2v[o[r]]+badd) per element (K=512)
// MODE 3: pool-divide — A[r][k] / max(CNT[r],1)
template<int TBM, int MR, int MODE>
__global__ __launch_bounds__(256, 2) void gemm_k(
    const float* __restrict__ A, int lda,
    const float* __restrict__ Tab, int KA, int DWc,
    const int* __restrict__ idx, int idxStride,
    const float* __restrict__ P1v, const float* __restrict__ P2v,
    const int* __restrict__ rels, const float* __restrict__ badd,
    const int* __restrict__ CNT,
    const float* __restrict__ W,
    const float* __restrict__ bias, int doRelu,
    float* __restrict__ C, int ldc,
    int M, int N, int K)
{
    __shared__ float As[TBK][TBM + 4];
    __shared__ float Bs[TBK][TBN + 4];
    const int tx = threadIdx.x, ty = threadIdx.y;
    const int tid = ty * 16 + tx;
    const int n0 = blockIdx.x * TBN, m0 = blockIdx.y * TBM;

    constexpr int LOADS = (TBM * TBK) / (256 * 4);   // 2 for TBM=128, 1 for TBM=64
    const int aRow = (MR == 8) ? (tid >> 1) : (tid >> 2);
    const int aK0  = (MR == 8) ? ((tid & 1) * 8) : ((tid & 3) * 4);
    const int bK = tid >> 4, bC = (tid & 15) << 2;

    const int r = m0 + aRow;
    const bool rOK = r < M;
    const int rr = rOK ? r : 0;

    // per-row aux, hoisted out of the K loop
    const float* aRowP = A + (size_t)rr * lda;
    const float* tabRowP = nullptr;
    const float* p1RowP = nullptr;
    const float* p2RowP = nullptr;
    float cf = 1.f;
    if constexpr (MODE == 1)
        tabRowP = Tab + (size_t)idx[(size_t)rr * idxStride] * DWc;
    if constexpr (MODE == 2) {
        p1RowP = P1v + (size_t)rels[3 * rr + 0] * HH_;
        p2RowP = P2v + (size_t)rels[3 * rr + 2] * HH_;
    }
    if constexpr (MODE == 3) { int c = CNT[rr]; cf = (float)(c < 1 ? 1 : c); }

    auto loadA4 = [&](int k) -> float4 {
        if constexpr (MODE == 0) {
            return ld4(aRowP + k);
        } else if constexpr (MODE == 1) {
            if (k < KA) return ld4(aRowP + k);
            return ld4(tabRowP + (k - KA));
        } else if constexpr (MODE == 2) {
            float4 vp = ld4(aRowP + k);
            float4 v1 = ld4(p1RowP + k);
            float4 v2 = ld4(p2RowP + k);
            float4 vb = ld4(badd + k);
            float4 rv;
            rv.x = fmaxf(v1.x + vp.x + v2.x + vb.x, 0.f);
            rv.y = fmaxf(v1.y + vp.y + v2.y + vb.y, 0.f);
            rv.z = fmaxf(v1.z + vp.z + v2.z + vb.z, 0.f);
            rv.w = fmaxf(v1.w + vp.w + v2.w + vb.w, 0.f);
            return rv;
        } else {
            float4 v = ld4(aRowP + k);
            v.x /= cf; v.y /= cf; v.z /= cf; v.w /= cf;
            return v;
        }
    };

    double dacc[MR][4];
    float  facc[MR][4];
#pragma unroll
    for (int i = 0; i < MR; i++)
#pragma unroll
        for (int j = 0; j < 4; j++) { dacc[i][j] = 0.0; facc[i][j] = 0.f; }

    const int tiles = (K + TBK - 1) / TBK;
    for (int t = 0; t < tiles; t++) {
        const int k0 = t * TBK;
        // ---- stage A ----
#pragma unroll
        for (int l = 0; l < LOADS; l++) {
            const int kk = aK0 + l * 4;
            const int k = k0 + kk;
            float4 av = make_float4(0.f, 0.f, 0.f, 0.f);
            if (rOK && k < K) av = loadA4(k);   // K%4==0 always
            As[kk + 0][aRow] = av.x;
            As[kk + 1][aRow] = av.y;
            As[kk + 2][aRow] = av.z;
            As[kk + 3][aRow] = av.w;
        }
        // ---- stage B ----
        {
            const int kb = k0 + bK;
            float4 bv = make_float4(0.f, 0.f, 0.f, 0.f);
            if (kb < K) bv = ld4(W + (size_t)kb * N + n0 + bC);
            *(float4*)&Bs[bK][bC] = bv;
        }
        __syncthreads();

        // ---- compute ----
#pragma unroll
        for (int kk = 0; kk < TBK; kk++) {
            const float4 b = *(const float4*)&Bs[kk][tx << 2];
            const float br[4] = {b.x, b.y, b.z, b.w};
#pragma unroll
            for (int mi = 0; mi < MR / 4; mi++) {
                const float4 a = *(const float4*)&As[kk][ty * MR + mi * 4];
                const float ar[4] = {a.x, a.y, a.z, a.w};
#pragma unroll
                for (int i = 0; i < 4; i++)
#pragma unroll
                    for (int j = 0; j < 4; j++)
                        facc[mi * 4 + i][j] = fmaf(ar[i], br[j], facc[mi * 4 + i][j]);
            }
        }
        // promote to fp64 every 2 tiles (K=32 fp32 chunks)
        if ((t & 1) || (t == tiles - 1)) {
#pragma unroll
            for (int i = 0; i < MR; i++)
#pragma unroll
                for (int j = 0; j < 4; j++) {
                    dacc[i][j] += (double)facc[i][j];
                    facc[i][j] = 0.f;
                }
        }
        __syncthreads();
    }

    // ---- epilogue ----
#pragma unroll
    for (int i = 0; i < MR; i++) {
        const int row = m0 + ty * MR + i;
        if (row < M) {
            float v[4];
#pragma unroll
            for (int j = 0; j < 4; j++) {
                double x = dacc[i][j];
                if (bias) x += (double)bias[n0 + (tx << 2) + j];
                float f = (float)x;
                if (doRelu) f = fmaxf(f, 0.f);
                v[j] = f;
            }
            float4 o4; o4.x = v[0]; o4.y = v[1]; o4.z = v[2]; o4.w = v[3];
            *(float4*)(C + (size_t)row * ldc + n0 + (tx << 2)) = o4;
        }
    }
}

__global__ void count_edges(const int* __restrict__ rels, int* __restrict__ CNT)
{
    int e = blockIdx.x * 256 + threadIdx.x;
    if (e >= T_N) return;
    atomicAdd(CNT + rels[3 * e + 0], 1);
    atomicAdd(CNT + rels[3 * e + 2], 1);
}

// pooled[s[e]] += t2[e,0:512]; pooled[o[e]] += t2[e,1024:1536]  (fp32 HW atomics)
__global__ void scatter_pool(const float* __restrict__ T2,
                             const int* __restrict__ rels,
                             float* __restrict__ PO)
{
    int e = blockIdx.x;
    int t = threadIdx.x;            // 256
    int s = rels[e * 3 + 0];
    int o = rels[e * 3 + 2];
#pragma unroll
    for (int u = 0; u < 2; u++) {
        int j = t + u * 256;
        unsafeAtomicAdd(PO + (size_t)s * HH_ + j, T2[(size_t)e * 1536 + j]);
        unsafeAtomicAdd(PO + (size_t)o * HH_ + j, T2[(size_t)e * 1536 + 1024 + j]);
    }
}

// dst[e, 0:512] = T2[e, 512:1024]
__global__ void copy_pred(const float* __restrict__ T2, float* __restrict__ dst)
{
    int i = blockIdx.x * 256 + threadIdx.x;   // float4 index
    if (i >= T_N * HH_ / 4) return;
    int e = i / (HH_ / 4);
    int j = (i % (HH_ / 4)) << 2;
    float4 v = *(const float4*)(T2 + (size_t)e * 1536 + 512 + j);
    *(float4*)(dst + (size_t)e * HH_ + j) = v;
}

template<int TBM, int MR, int MODE>
static inline void G(hipStream_t st, const float* A, int lda,
                     const float* Tab, int KA, int DWc,
                     const int* idx, int idxs,
                     const float* P1v, const float* P2v,
                     const int* rels, const float* badd, const int* CNT,
                     const float* W, const float* bias, int relu_,
                     float* C, int ldc, int M, int N, int K)
{
    dim3 g(N / TBN, (M + TBM - 1) / TBM), b(16, 16);
    gemm_k<TBM, MR, MODE><<<g, b, 0, st>>>(A, lda, Tab, KA, DWc, idx, idxs,
                                           P1v, P2v, rels, badd, CNT,
                                           W, bias, relu_, C, ldc, M, N, K);
}

extern "C" void kernel_launch(void* const* d_in, const int* in_sizes, int n_in,
                              void* d_out, int out_size, void* d_ws, size_t ws_size,
                              hipStream_t stream)
{
    const float* obj_embs  = (const float*)d_in[0];
    const float* pred_embs = (const float*)d_in[2];
    const int*   rels      = (const int*)d_in[4];
    const int*   objs      = (const int*)d_in[5];
    const float* obj_table = (const float*)d_in[6];
    const float* rel_table = (const float*)d_in[7];
    const float* Wf_obj = (const float*)d_in[8];
    const float* bf_obj = (const float*)d_in[9];
    const float* Wf_rel = (const float*)d_in[10];
    const float* bf_rel = (const float*)d_in[11];
    const float* W1a = (const float*)d_in[12];
    const float* b1a = (const float*)d_in[13];
    const float* W1b = (const float*)d_in[14];
    const float* b1b = (const float*)d_in[15];
    const float* W2a = (const float*)d_in[16];
    const float* b2a = (const float*)d_in[17];
    const float* W2b = (const float*)d_in[18];
    const float* b2b = (const float*)d_in[19];
    const float* Ws1a = (const float*)d_in[20];
    const float* bs1a = (const float*)d_in[21];
    const float* Ws1b = (const float*)d_in[22];
    const float* bs1b = (const float*)d_in[23];
    const float* Ws2a = (const float*)d_in[24];
    const float* bs2a = (const float*)d_in[25];
    const float* Ws2b = (const float*)d_in[26];
    const float* bs2b = (const float*)d_in[27];
    float* out = (float*)d_out;

    // workspace layout (fp32), ~127 MB
    float* base = (float*)d_ws;
    float* OV = base;                              // 2000*2048
    float* PV = OV + (size_t)O_N * DIN;            // 6000*2048
    float* P1 = PV + (size_t)T_N * DIN;            // 2000*512
    float* P2 = P1 + (size_t)O_N * HH_;            // 2000*512
    float* PP = P2 + (size_t)O_N * HH_;            // 6000*512
    float* T2 = PP + (size_t)T_N * HH_;            // 6000*1536
    float* PO = T2 + (size_t)T_N * 1536;           // 2000*512
    int* CNT = (int*)(PO + (size_t)O_N * HH_);     // 2000 ints

    // edge counts — s,o are fixed for the whole call, compute once
    hipMemsetAsync(CNT, 0, (size_t)O_N * sizeof(int), stream);
    hipLaunchKernelGGL(count_edges, dim3((T_N + 255) / 256), dim3(256), 0, stream,
                       rels, CNT);

    // input projections (concat with table lookup fused into A-load)
    G<128, 8, 1>(stream, obj_embs, DIN, obj_table, DIN, DW, objs, 1,
                 nullptr, nullptr, nullptr, nullptr, nullptr,
                 Wf_obj, bf_obj, 1, OV, DIN, O_N, DIN, DIN + DW);
    G<128, 8, 1>(stream, pred_embs, DIN, rel_table, DIN, DW, rels + 1, 3,
                 nullptr, nullptr, nullptr, nullptr, nullptr,
                 Wf_rel, bf_rel, 1, PV, DIN, T_N, DIN, DIN + DW);

    for (int L = 0; L < 5; L++) {
        const int D = (L == 0) ? DIN : HH_;
        const float* w1a  = (L == 0) ? W1a : (Ws1a + (size_t)(L - 1) * 3 * HH_ * HH_);
        const float* bb1a = (L == 0) ? b1a : (bs1a + (size_t)(L - 1) * HH_);
        const float* w1b  = (L == 0) ? W1b : (Ws1b + (size_t)(L - 1) * HH_ * 1536);
        const float* bb1b = (L == 0) ? b1b : (bs1b + (size_t)(L - 1) * 1536);
        const float* w2a  = (L == 0) ? W2a : (Ws2a + (size_t)(L - 1) * HH_ * HH_);
        const float* bb2a = (L == 0) ? b2a : (bs2a + (size_t)(L - 1) * HH_);
        const float* w2b  = (L == 0) ? W2b : (Ws2b + (size_t)(L - 1) * HH_ * DG);
        const float* bb2b = (L == 0) ? b2b : (bs2b + (size_t)(L - 1) * DG);
        const float* w1a_top = w1a;
        const float* w1a_mid = w1a + (size_t)D * HH_;
        const float* w1a_bot = w1a + (size_t)2 * D * HH_;

        // cur @ W1a decomposed into per-object / per-edge matmuls
        G<64, 4, 0>(stream, OV, D, nullptr, 0, 0, nullptr, 0,
                    nullptr, nullptr, nullptr, nullptr, nullptr,
                    w1a_top, nullptr, 0, P1, HH_, O_N, HH_, D);
        G<128, 8, 0>(stream, PV, D, nullptr, 0, 0, nullptr, 0,
                     nullptr, nullptr, nullptr, nullptr, nullptr,
                     w1a_mid, nullptr, 0, PP, HH_, T_N, HH_, D);
        G<64, 4, 0>(stream, OV, D, nullptr, 0, 0, nullptr, 0,
                    nullptr, nullptr, nullptr, nullptr, nullptr,
                    w1a_bot, nullptr, 0, P2, HH_, O_N, HH_, D);

        // t2 = relu( relu(P1[s]+PP+P2[o]+b1a) @ W1b + b1b )  — edge-combine fused
        G<128, 8, 2>(stream, PP, HH_, nullptr, 0, 0, nullptr, 0,
                     P1, P2, rels, bb1a, nullptr,
                     w1b, bb1b, 1, T2, 1536, T_N, 1536, HH_);

        // pooling (fp32 HW atomics)
        hipMemsetAsync(PO, 0, (size_t)O_N * HH_ * sizeof(float), stream);
        hipLaunchKernelGGL(scatter_pool, dim3(T_N), dim3(256), 0, stream,
                           T2, rels, PO);

        // obj MLP2: h = relu((PO/cnt)@W2a+b2a) -> P1 (reuse), obj = relu(h@W2b+b2b)
        G<64, 4, 3>(stream, PO, HH_, nullptr, 0, 0, nullptr, 0,
                    nullptr, nullptr, nullptr, nullptr, CNT,
                    w2a, bb2a, 1, P1, HH_, O_N, HH_, HH_);
        float* objDst = (L == 4) ? out : OV;
        G<64, 4, 0>(stream, P1, HH_, nullptr, 0, 0, nullptr, 0,
                    nullptr, nullptr, nullptr, nullptr, nullptr,
                    w2b, bb2b, 1, objDst, HH_, O_N, DG, HH_);

        float* predDst = (L == 4) ? (out + (size_t)O_N * DG) : PV;
        hipLaunchKernelGGL(copy_pred, dim3((T_N * HH_ / 4 + 255) / 256), dim3(256), 0, stream,
                           T2, predDst);
    }
}